// Round 6
// baseline (196.088 us; speedup 1.0000x reference)
//
#include <hip/hip_runtime.h>

// RankingLoss on MI355X.
// inputs: out1 [8192,128] f32, out2 [8192,128] f32, anchor1 [512] i32, anchor2 [512] i32
// output: scalar f32 loss.
//
// R6: (a) select_kernel: one wave per row, ballot+popcount counting (count
// lands in SGPRs via v_cmp + s_bcnt1_b64) -> zero barriers, zero shuffle
// chains in the 31-round search. R5's select was ~70-90us: 1 wave/SIMD with
// 6-deep ds_bpermute reduce chains x31 rounds had no latency hiding.
// (b) dist staging writes widened to ds_write_b128 (8 dims/lane per write,
// stride-20 rows): 2-way banks (free) vs R5's 4-way b64 writes (6M conflicts).
// R5 history: f16 pk_sub+and+fdot2 core (1.5 inst/2dims), no spill, LDS
// b128 reads 2-way free.

#define NN 8192      // nodes
#define DF 128       // feature dim
#define NA 512       // anchors
#define KK 32        // negatives per anchor

typedef _Float16 h2 __attribute__((ext_vector_type(2)));

// ---------------- helpers ----------------

__device__ __forceinline__ float wave_reduce_f(float x) {
#pragma unroll
  for (int off = 32; off > 0; off >>= 1) x += __shfl_down(x, off);
  return x;
}

__device__ __forceinline__ int wave_reduce_i(int x) {
#pragma unroll
  for (int off = 32; off > 0; off >>= 1) x += __shfl_down(x, off);
  return x;
}

// acc += |a-b|.lo + |a-b|.hi  for packed f16 pairs, f32 accumulate.
__device__ __forceinline__ float absdiff_dot2(unsigned a, unsigned b,
                                              float acc) {
  h2 ha = __builtin_bit_cast(h2, a);
  h2 hb = __builtin_bit_cast(h2, b);
  h2 d = ha - hb;                                        // v_pk_add_f16 (neg)
  unsigned m = __builtin_bit_cast(unsigned, d) & 0x7FFF7FFFu;  // packed abs
  h2 ad = __builtin_bit_cast(h2, m);
  const h2 one = {(_Float16)1.0f, (_Float16)1.0f};
  return __builtin_amdgcn_fdot2(ad, one, acc, false);    // v_dot2_f32_f16
}

__device__ __forceinline__ unsigned cvt2_f16(float x, float y) {
  return __builtin_bit_cast(unsigned, __builtin_amdgcn_cvt_pkrtz(x, y));
}

// 8 dims (two float4) -> uint4 of packed f16 pairs
__device__ __forceinline__ uint4 cvt8_f16(float4 v0, float4 v1) {
  uint4 r;
  r.x = cvt2_f16(v0.x, v0.y);
  r.y = cvt2_f16(v0.z, v0.w);
  r.z = cvt2_f16(v1.x, v1.y);
  r.w = cvt2_f16(v1.z, v1.w);
  return r;
}

// ---------------- kernel 1: distance matrix ----------------
// grid: (64 node tiles, 8 anchor tiles, 2 dirs) = 1024 blocks, block 256.
// Tile: 128 nodes x 64 anchors; dims chunked by 32 through LDS as packed f16
// (stride 20 uints; b128 reads AND writes both <=2-way banked). 8x4 f32 acc.
// Epilogue: f32 LDS-transpose staging then coalesced dwordx4 stores.

__global__ __launch_bounds__(256, 3) void dist_kernel(
    const float* __restrict__ out1, const float* __restrict__ out2,
    const int* __restrict__ anchor1, const int* __restrict__ anchor2,
    float* __restrict__ dist) {
  const int tid = threadIdx.x;
  const int nb = blockIdx.x;   // node tile
  const int ab = blockIdx.y;   // anchor tile
  const int dir = blockIdx.z;  // 0: a1 vs out2, 1: a2 vs out1
  const float* nodes = dir ? out1 : out2;
  const float* asrc = dir ? out2 : out1;
  const int* aidx = dir ? anchor2 : anchor1;
  const int n0 = nb * 128;
  const int a0 = ab * 64;

  __shared__ union {
    struct {
      unsigned nds[128][20];  // node rows: 16 uints = 32 f16 dims + pad
      unsigned ads[64][20];   // anchor rows
    } t;
    float stage[32][136];  // epilogue transpose staging (2-way banks, free)
  } sm;
  __shared__ int aind[64];

  if (tid < 64) aind[tid] = aidx[a0 + tid];

  float acc[8][4];
#pragma unroll
  for (int i = 0; i < 8; ++i)
#pragma unroll
    for (int j = 0; j < 4; ++j) acc[i][j] = 0.f;

  const int tn = tid & 15;  // node group:   cols tn + 16*i
  const int ta = tid >> 4;  // anchor group: rows ta + 16*j

  for (int cch = 0; cch < 4; ++cch) {
    const int d0 = cch * 32;
    __syncthreads();  // prev chunk's readers done (also covers aind preload)
    // Node tile: 128 rows x 4 uint4-slots = 512 slots; 2 per thread.
#pragma unroll
    for (int r = 0; r < 2; ++r) {
      const int f = tid + 256 * r;
      const int row = f >> 2;  // 0..127
      const int q = f & 3;     // 0..3 (8 dims each)
      const float* src = nodes + (size_t)(n0 + row) * DF + d0 + q * 8;
      const float4 v0 = *(const float4*)(src);
      const float4 v1 = *(const float4*)(src + 4);
      *(uint4*)&sm.t.nds[row][q * 4] = cvt8_f16(v0, v1);  // ds_write_b128
    }
    // Anchor tile: 64 rows x 4 slots = 256 slots; 1 per thread.
    {
      const int row = tid >> 2;  // 0..63
      const int q = tid & 3;
      const float* src = asrc + (size_t)aind[row] * DF + d0 + q * 8;
      const float4 v0 = *(const float4*)(src);
      const float4 v1 = *(const float4*)(src + 4);
      *(uint4*)&sm.t.ads[row][q * 4] = cvt8_f16(v0, v1);
    }
    __syncthreads();
#pragma unroll
    for (int d8 = 0; d8 < 4; ++d8) {  // 8 dims (4 uints) per step
      uint4 nv[8], av[4];
#pragma unroll
      for (int i = 0; i < 8; ++i)
        nv[i] = *(const uint4*)&sm.t.nds[tn + 16 * i][d8 * 4];
#pragma unroll
      for (int j = 0; j < 4; ++j)
        av[j] = *(const uint4*)&sm.t.ads[ta + 16 * j][d8 * 4];
#pragma unroll
      for (int i = 0; i < 8; ++i)
#pragma unroll
        for (int j = 0; j < 4; ++j) {
          acc[i][j] = absdiff_dot2(nv[i].x, av[j].x, acc[i][j]);
          acc[i][j] = absdiff_dot2(nv[i].y, av[j].y, acc[i][j]);
          acc[i][j] = absdiff_dot2(nv[i].z, av[j].z, acc[i][j]);
          acc[i][j] = absdiff_dot2(nv[i].w, av[j].w, acc[i][j]);
        }
    }
  }

  // Epilogue: two 32-row halves through LDS, then coalesced dwordx4 stores.
  const size_t rowbase = (size_t)(dir * NA + a0) * NN + n0;
#pragma unroll
  for (int half = 0; half < 2; ++half) {
    __syncthreads();  // tiles / previous stage fully consumed
#pragma unroll
    for (int j = 0; j < 2; ++j) {
      const int jj = half * 2 + j;
#pragma unroll
      for (int i = 0; i < 8; ++i)
        sm.stage[ta + 16 * j][tn + 16 * i] = acc[i][jj];
    }
    __syncthreads();
#pragma unroll
    for (int s = 0; s < 4; ++s) {
      const int f = tid + 256 * s;  // 0..1023 float4 slots
      const int row = f >> 5;       // 0..31
      const int c4 = f & 31;        // 0..31
      const float4 v = *(const float4*)&sm.stage[row][c4 * 4];
      *(float4*)(dist + rowbase + (size_t)(half * 32 + row) * NN + c4 * 4) = v;
    }
  }
}

// ---------------- kernel 2: selection + loss ----------------
// grid: 1024 blocks x 64 threads (ONE wave per row). Row's 8192 distances in
// VGPRs (128/lane). Counting via ballot+popcount -> SGPRs: no barriers, no
// shuffle chains. Outer 31-round loop not unrolled (small I-footprint).

__global__ __launch_bounds__(64) void select_kernel(
    const float* __restrict__ dist, const float* __restrict__ out1,
    const float* __restrict__ out2, const int* __restrict__ anchor1,
    const int* __restrict__ anchor2, float* __restrict__ out) {
  const int lane = threadIdx.x;
  const int row = blockIdx.x;  // 0..1023
  const int a = row & (NA - 1);

  unsigned u[128];
  const float4* drow = (const float4*)(dist + (size_t)row * NN);
#pragma unroll
  for (int g = 0; g < 32; ++g) {
    const float4 t = drow[lane + 64 * g];
    u[4 * g + 0] = __float_as_uint(t.x);
    u[4 * g + 1] = __float_as_uint(t.y);
    u[4 * g + 2] = __float_as_uint(t.z);
    u[4 * g + 3] = __float_as_uint(t.w);
  }

  // D = L1(out1[anchor1[a]], out2[anchor2[a]]) + margin, exact f32.
  const int r1 = anchor1[a];
  const int r2 = anchor2[a];
  float p = fabsf(out1[(size_t)r1 * DF + lane] - out2[(size_t)r2 * DF + lane]) +
            fabsf(out1[(size_t)r1 * DF + 64 + lane] -
                  out2[(size_t)r2 * DF + 64 + lane]);
  p = wave_reduce_f(p);
  const float Dv = __shfl(p, 0) + 1.0f;  // MARGIN

  // Bitwise binary search for T = 32nd smallest (bit 31 is 0: dists >= 0).
  // count(u < P) < KK invariant; final P = 32nd-smallest bit pattern.
  unsigned P = 0;
#pragma unroll 1
  for (int b = 30; b >= 0; --b) {
    const unsigned mid = P | (1u << b);
    int c = 0;
#pragma unroll
    for (int i = 0; i < 128; ++i)
      c += (int)__popcll(__ballot(u[i] < mid));  // scalar, wave-uniform
    if (c < KK) P = mid;  // uniform branch
  }

  // Sum relu(D - d) over d < P; count via ballot; ties at P analytic.
  float s = 0.f;
  int c = 0;
#pragma unroll
  for (int i = 0; i < 128; ++i) {
    c += (int)__popcll(__ballot(u[i] < P));
    if (u[i] < P) {
      const float t = Dv - __uint_as_float(u[i]);
      s += (t > 0.f) ? t : 0.f;
    }
  }
  s = wave_reduce_f(s);  // full sum lands in lane 0
  if (lane == 0) {
    float tt = Dv - __uint_as_float(P);
    if (tt < 0.f) tt = 0.f;
    const float stot = s + (float)(KK - c) * tt;
    atomicAdd(out, stot * (1.0f / (float)(NA * KK)));
  }
}

// ---------------- fallback: fused (no workspace), block-wide ----------------

__device__ __forceinline__ float compute_D_block(
    const float* __restrict__ out1, const float* __restrict__ out2,
    const int* __restrict__ anchor1, const int* __restrict__ anchor2, int a) {
  __shared__ float dred[4];
  const int tid = threadIdx.x;
  float p = 0.f;
  if (tid < DF) {
    const int r1 = anchor1[a];
    const int r2 = anchor2[a];
    p = fabsf(out1[(size_t)r1 * DF + tid] - out2[(size_t)r2 * DF + tid]);
  }
  p = wave_reduce_f(p);
  const int lane = tid & 63, wid = tid >> 6;
  if (lane == 0) dred[wid] = p;
  __syncthreads();
  return dred[0] + dred[1] + dred[2] + dred[3] + 1.0f;
}

__global__ __launch_bounds__(256) void fused_kernel(
    const float* __restrict__ out1, const float* __restrict__ out2,
    const int* __restrict__ anchor1, const int* __restrict__ anchor2,
    float* __restrict__ out) {
  const int tid = threadIdx.x;
  const int row = blockIdx.x;  // 0..1023
  const int dir = row >> 9;
  const int a = row & (NA - 1);
  const float* nodes = dir ? out1 : out2;
  const float* asrc = dir ? out2 : out1;
  const int* aidx = dir ? anchor2 : anchor1;

  __shared__ float ars[DF];
  __shared__ int redi[4];
  __shared__ float redf[4];
  if (tid < DF / 4) {
    const int arow = aidx[a];
    *(float4*)&ars[tid * 4] =
        *(const float4*)(asrc + (size_t)arow * DF + tid * 4);
  }
  __syncthreads();

  unsigned u[32];
  for (int i = 0; i < 32; ++i) {
    const int n = tid + 256 * i;
    const float4* nrow = (const float4*)(nodes + (size_t)n * DF);
    float dsum = 0.f;
    for (int d4 = 0; d4 < DF / 4; ++d4) {
      const float4 t = nrow[d4];
      const float4 av = *(const float4*)&ars[d4 * 4];
      dsum += fabsf(t.x - av.x) + fabsf(t.y - av.y) + fabsf(t.z - av.z) +
              fabsf(t.w - av.w);
    }
    u[i] = __float_as_uint(dsum);
  }
  __syncthreads();

  const float Dv = compute_D_block(out1, out2, anchor1, anchor2, a);
  const int lane = tid & 63, wid = tid >> 6;

  unsigned P = 0;
#pragma unroll 1
  for (int b = 30; b >= 0; --b) {
    const unsigned mid = P | (1u << b);
    int c = 0;
#pragma unroll
    for (int i = 0; i < 32; ++i) c += (u[i] < mid) ? 1 : 0;
    c = wave_reduce_i(c);
    __syncthreads();
    if (lane == 0) redi[wid] = c;
    __syncthreads();
    const int tot = redi[0] + redi[1] + redi[2] + redi[3];
    if (tot < KK) P = mid;
  }

  float s = 0.f;
  int c = 0;
#pragma unroll
  for (int i = 0; i < 32; ++i) {
    if (u[i] < P) {
      const float t = Dv - __uint_as_float(u[i]);
      s += (t > 0.f) ? t : 0.f;
      c += 1;
    }
  }
  s = wave_reduce_f(s);
  c = wave_reduce_i(c);
  __syncthreads();
  if (lane == 0) {
    redf[wid] = s;
    redi[wid] = c;
  }
  __syncthreads();
  if (tid == 0) {
    float stot = redf[0] + redf[1] + redf[2] + redf[3];
    const int ctot = redi[0] + redi[1] + redi[2] + redi[3];
    float tt = Dv - __uint_as_float(P);
    if (tt < 0.f) tt = 0.f;
    stot += (float)(KK - ctot) * tt;
    atomicAdd(out, stot * (1.0f / (float)(NA * KK)));
  }
}

// ---------------- launch ----------------

extern "C" void kernel_launch(void* const* d_in, const int* in_sizes, int n_in,
                              void* d_out, int out_size, void* d_ws,
                              size_t ws_size, hipStream_t stream) {
  const float* out1 = (const float*)d_in[0];
  const float* out2 = (const float*)d_in[1];
  const int* anchor1 = (const int*)d_in[2];
  const int* anchor2 = (const int*)d_in[3];
  float* out = (float*)d_out;

  (void)hipMemsetAsync(d_out, 0, sizeof(float), stream);

  const size_t need = (size_t)2 * NA * NN * sizeof(float);  // 32 MB
  if (ws_size >= need) {
    float* dist = (float*)d_ws;
    dim3 g1(NN / 128, NA / 64, 2);
    dist_kernel<<<g1, 256, 0, stream>>>(out1, out2, anchor1, anchor2, dist);
    select_kernel<<<2 * NA, 64, 0, stream>>>(dist, out1, out2, anchor1,
                                             anchor2, out);
  } else {
    fused_kernel<<<2 * NA, 256, 0, stream>>>(out1, out2, anchor1, anchor2, out);
  }
}

// Round 7
// 155.514 us; speedup vs baseline: 1.2609x; 1.2609x over previous
//
#include <hip/hip_runtime.h>

// RankingLoss on MI355X.
// inputs: out1 [8192,128] f32, out2 [8192,128] f32, anchor1 [512] i32, anchor2 [512] i32
// output: scalar f32 loss.
//
// R7: select_kernel rewritten as candidate pre-filter. R6 post-mortem: with
// u[128]/lane the compiler allocated only 72 VGPRs and re-streamed the row
// from L2 on EVERY one of 31 search rounds (~1GB/kernel through L2; latency-
// bound at 4 waves/CU) -> 71us. New select: (1) stream row once, per-lane
// umin; (2) T = exact 32nd-smallest of the 64 lane minima (31 rounds x ONE
// ballot) -- guaranteed upper bound on the global 32nd smallest, E[#cand]=
// 64*ln2~44; (3) re-stream, compact candidates u<=T to LDS (wave atomics);
// (4) exact bitwise search + tie-analytic loss over <=256 candidates (4/lane
// in VGPRs). Streaming full-search fallback if C>256 (adversarial only).
// dist_kernel unchanged from R6 (f16 fdot2 core, b128 LDS writes).

#define NN 8192      // nodes
#define DF 128       // feature dim
#define NA 512       // anchors
#define KK 32        // negatives per anchor
#define CCAP 256     // candidate capacity (E[C]~44; fallback if exceeded)

typedef _Float16 h2 __attribute__((ext_vector_type(2)));

// ---------------- helpers ----------------

__device__ __forceinline__ float wave_reduce_f(float x) {
#pragma unroll
  for (int off = 32; off > 0; off >>= 1) x += __shfl_down(x, off);
  return x;
}

__device__ __forceinline__ int wave_reduce_i(int x) {
#pragma unroll
  for (int off = 32; off > 0; off >>= 1) x += __shfl_down(x, off);
  return x;
}

__device__ __forceinline__ unsigned umin2(unsigned a, unsigned b) {
  return a < b ? a : b;
}

// acc += |a-b|.lo + |a-b|.hi  for packed f16 pairs, f32 accumulate.
__device__ __forceinline__ float absdiff_dot2(unsigned a, unsigned b,
                                              float acc) {
  h2 ha = __builtin_bit_cast(h2, a);
  h2 hb = __builtin_bit_cast(h2, b);
  h2 d = ha - hb;                                        // v_pk_add_f16 (neg)
  unsigned m = __builtin_bit_cast(unsigned, d) & 0x7FFF7FFFu;  // packed abs
  h2 ad = __builtin_bit_cast(h2, m);
  const h2 one = {(_Float16)1.0f, (_Float16)1.0f};
  return __builtin_amdgcn_fdot2(ad, one, acc, false);    // v_dot2_f32_f16
}

__device__ __forceinline__ unsigned cvt2_f16(float x, float y) {
  return __builtin_bit_cast(unsigned, __builtin_amdgcn_cvt_pkrtz(x, y));
}

// 8 dims (two float4) -> uint4 of packed f16 pairs
__device__ __forceinline__ uint4 cvt8_f16(float4 v0, float4 v1) {
  uint4 r;
  r.x = cvt2_f16(v0.x, v0.y);
  r.y = cvt2_f16(v0.z, v0.w);
  r.z = cvt2_f16(v1.x, v1.y);
  r.w = cvt2_f16(v1.z, v1.w);
  return r;
}

// ---------------- kernel 1: distance matrix (unchanged from R6) -------------
// grid: (64 node tiles, 8 anchor tiles, 2 dirs) = 1024 blocks, block 256.
// Tile: 128 nodes x 64 anchors; dims chunked by 32 through LDS as packed f16
// (stride 20 uints; b128 reads AND writes both <=2-way banked). 8x4 f32 acc.
// Epilogue: f32 LDS-transpose staging then coalesced dwordx4 stores.

__global__ __launch_bounds__(256, 3) void dist_kernel(
    const float* __restrict__ out1, const float* __restrict__ out2,
    const int* __restrict__ anchor1, const int* __restrict__ anchor2,
    float* __restrict__ dist) {
  const int tid = threadIdx.x;
  const int nb = blockIdx.x;   // node tile
  const int ab = blockIdx.y;   // anchor tile
  const int dir = blockIdx.z;  // 0: a1 vs out2, 1: a2 vs out1
  const float* nodes = dir ? out1 : out2;
  const float* asrc = dir ? out2 : out1;
  const int* aidx = dir ? anchor2 : anchor1;
  const int n0 = nb * 128;
  const int a0 = ab * 64;

  __shared__ union {
    struct {
      unsigned nds[128][20];  // node rows: 16 uints = 32 f16 dims + pad
      unsigned ads[64][20];   // anchor rows
    } t;
    float stage[32][136];  // epilogue transpose staging (2-way banks, free)
  } sm;
  __shared__ int aind[64];

  if (tid < 64) aind[tid] = aidx[a0 + tid];

  float acc[8][4];
#pragma unroll
  for (int i = 0; i < 8; ++i)
#pragma unroll
    for (int j = 0; j < 4; ++j) acc[i][j] = 0.f;

  const int tn = tid & 15;  // node group:   cols tn + 16*i
  const int ta = tid >> 4;  // anchor group: rows ta + 16*j

  for (int cch = 0; cch < 4; ++cch) {
    const int d0 = cch * 32;
    __syncthreads();  // prev chunk's readers done (also covers aind preload)
    // Node tile: 128 rows x 4 uint4-slots = 512 slots; 2 per thread.
#pragma unroll
    for (int r = 0; r < 2; ++r) {
      const int f = tid + 256 * r;
      const int row = f >> 2;  // 0..127
      const int q = f & 3;     // 0..3 (8 dims each)
      const float* src = nodes + (size_t)(n0 + row) * DF + d0 + q * 8;
      const float4 v0 = *(const float4*)(src);
      const float4 v1 = *(const float4*)(src + 4);
      *(uint4*)&sm.t.nds[row][q * 4] = cvt8_f16(v0, v1);  // ds_write_b128
    }
    // Anchor tile: 64 rows x 4 slots = 256 slots; 1 per thread.
    {
      const int row = tid >> 2;  // 0..63
      const int q = tid & 3;
      const float* src = asrc + (size_t)aind[row] * DF + d0 + q * 8;
      const float4 v0 = *(const float4*)(src);
      const float4 v1 = *(const float4*)(src + 4);
      *(uint4*)&sm.t.ads[row][q * 4] = cvt8_f16(v0, v1);
    }
    __syncthreads();
#pragma unroll
    for (int d8 = 0; d8 < 4; ++d8) {  // 8 dims (4 uints) per step
      uint4 nv[8], av[4];
#pragma unroll
      for (int i = 0; i < 8; ++i)
        nv[i] = *(const uint4*)&sm.t.nds[tn + 16 * i][d8 * 4];
#pragma unroll
      for (int j = 0; j < 4; ++j)
        av[j] = *(const uint4*)&sm.t.ads[ta + 16 * j][d8 * 4];
#pragma unroll
      for (int i = 0; i < 8; ++i)
#pragma unroll
        for (int j = 0; j < 4; ++j) {
          acc[i][j] = absdiff_dot2(nv[i].x, av[j].x, acc[i][j]);
          acc[i][j] = absdiff_dot2(nv[i].y, av[j].y, acc[i][j]);
          acc[i][j] = absdiff_dot2(nv[i].z, av[j].z, acc[i][j]);
          acc[i][j] = absdiff_dot2(nv[i].w, av[j].w, acc[i][j]);
        }
    }
  }

  // Epilogue: two 32-row halves through LDS, then coalesced dwordx4 stores.
  const size_t rowbase = (size_t)(dir * NA + a0) * NN + n0;
#pragma unroll
  for (int half = 0; half < 2; ++half) {
    __syncthreads();  // tiles / previous stage fully consumed
#pragma unroll
    for (int j = 0; j < 2; ++j) {
      const int jj = half * 2 + j;
#pragma unroll
      for (int i = 0; i < 8; ++i)
        sm.stage[ta + 16 * j][tn + 16 * i] = acc[i][jj];
    }
    __syncthreads();
#pragma unroll
    for (int s = 0; s < 4; ++s) {
      const int f = tid + 256 * s;  // 0..1023 float4 slots
      const int row = f >> 5;       // 0..31
      const int c4 = f & 31;        // 0..31
      const float4 v = *(const float4*)&sm.stage[row][c4 * 4];
      *(float4*)(dist + rowbase + (size_t)(half * 32 + row) * NN + c4 * 4) = v;
    }
  }
}

// ---------------- kernel 2: selection + loss (candidate pre-filter) --------
// grid: 1024 blocks x 64 threads (one wave per row). No large register
// arrays: two streaming passes over the row, then exact selection over the
// ~44 (cap 256) candidates <= T, where T = 32nd-smallest lane minimum
// (guaranteed upper bound on the global 32nd smallest).

__global__ __launch_bounds__(64) void select_kernel(
    const float* __restrict__ dist, const float* __restrict__ out1,
    const float* __restrict__ out2, const int* __restrict__ anchor1,
    const int* __restrict__ anchor2, float* __restrict__ out) {
  const int lane = threadIdx.x;
  const int row = blockIdx.x;  // 0..1023
  const int a = row & (NA - 1);

  __shared__ unsigned cand[CCAP];
  __shared__ int cnt;

  const uint4* drow = (const uint4*)(dist + (size_t)row * NN);

  // D = L1(out1[anchor1[a]], out2[anchor2[a]]) + margin, exact f32.
  const int r1 = anchor1[a];
  const int r2 = anchor2[a];
  float p = fabsf(out1[(size_t)r1 * DF + lane] - out2[(size_t)r2 * DF + lane]) +
            fabsf(out1[(size_t)r1 * DF + 64 + lane] -
                  out2[(size_t)r2 * DF + 64 + lane]);
  p = wave_reduce_f(p);
  const float Dv = __shfl(p, 0) + 1.0f;  // MARGIN

  // Pass 1: per-lane min over this lane's 128 values (4 indep chains).
  unsigned m0 = 0xFFFFFFFFu, m1 = 0xFFFFFFFFu, m2 = 0xFFFFFFFFu,
           m3 = 0xFFFFFFFFu;
#pragma unroll
  for (int g = 0; g < 32; ++g) {
    const uint4 t = drow[lane + 64 * g];
    m0 = umin2(m0, t.x);
    m1 = umin2(m1, t.y);
    m2 = umin2(m2, t.z);
    m3 = umin2(m3, t.w);
  }
  const unsigned mn = umin2(umin2(m0, m1), umin2(m2, m3));

  // T = exact 32nd-smallest of the 64 lane minima (one ballot per round).
  unsigned T = 0;
#pragma unroll 1
  for (int b = 30; b >= 0; --b) {
    const unsigned mid = T | (1u << b);
    if ((int)__popcll(__ballot(mn < mid)) < KK) T = mid;
  }
  // >=32 lanes have min <= T, each contributing >=1 value <= T:
  // global 32nd smallest <= T.

  // Pass 2: compact candidates (u <= T) into LDS. Wave-synchronous: the
  // cnt=0 store precedes all atomics in the single wave's program order.
  if (lane == 0) cnt = 0;
#pragma unroll
  for (int g = 0; g < 32; ++g) {
    const uint4 t = drow[lane + 64 * g];
    if (t.x <= T) { int q = atomicAdd(&cnt, 1); if (q < CCAP) cand[q] = t.x; }
    if (t.y <= T) { int q = atomicAdd(&cnt, 1); if (q < CCAP) cand[q] = t.y; }
    if (t.z <= T) { int q = atomicAdd(&cnt, 1); if (q < CCAP) cand[q] = t.z; }
    if (t.w <= T) { int q = atomicAdd(&cnt, 1); if (q < CCAP) cand[q] = t.w; }
  }
  __syncthreads();  // single wave: cheap; forces lgkmcnt drain before read
  const int C = cnt;

  if (C <= CCAP) {
    // Exact selection over candidates, 4 per lane (pad +inf pattern).
    unsigned v[4];
#pragma unroll
    for (int k = 0; k < 4; ++k)
      v[k] = (lane + 64 * k < C) ? cand[lane + 64 * k] : 0xFFFFFFFFu;

    // Counts over candidates == counts over full row for any probe mid <= T
    // (all values <= T are candidates); probes with mid > T return C >= 32
    // which matches the full count's >=32 decision. Search is exact.
    unsigned P = 0;
#pragma unroll 1
    for (int b = 30; b >= 0; --b) {
      const unsigned mid = P | (1u << b);
      int c = 0;
#pragma unroll
      for (int k = 0; k < 4; ++k)
        c += (int)__popcll(__ballot(v[k] < mid));
      if (c < KK) P = mid;
    }

    float s = 0.f;
    int c = 0;
#pragma unroll
    for (int k = 0; k < 4; ++k) {
      c += (int)__popcll(__ballot(v[k] < P));
      if (v[k] < P) {
        const float t = Dv - __uint_as_float(v[k]);
        s += (t > 0.f) ? t : 0.f;
      }
    }
    s = wave_reduce_f(s);
    if (lane == 0) {
      float tt = Dv - __uint_as_float(P);
      if (tt < 0.f) tt = 0.f;
      atomicAdd(out, (s + (float)(KK - c) * tt) * (1.0f / (float)(NA * KK)));
    }
  } else {
    // Fallback (adversarial/degenerate rows only): streaming full search.
    unsigned P = 0;
#pragma unroll 1
    for (int b = 30; b >= 0; --b) {
      const unsigned mid = P | (1u << b);
      int c = 0;
#pragma unroll 1
      for (int g = 0; g < 32; ++g) {
        const uint4 t = drow[lane + 64 * g];
        c += (int)__popcll(__ballot(t.x < mid));
        c += (int)__popcll(__ballot(t.y < mid));
        c += (int)__popcll(__ballot(t.z < mid));
        c += (int)__popcll(__ballot(t.w < mid));
      }
      if (c < KK) P = mid;
    }
    float s = 0.f;
    int c = 0;
#pragma unroll 1
    for (int g = 0; g < 32; ++g) {
      const uint4 t = drow[lane + 64 * g];
      const unsigned vv[4] = {t.x, t.y, t.z, t.w};
#pragma unroll
      for (int k = 0; k < 4; ++k) {
        c += (int)__popcll(__ballot(vv[k] < P));
        if (vv[k] < P) {
          const float tt = Dv - __uint_as_float(vv[k]);
          s += (tt > 0.f) ? tt : 0.f;
        }
      }
    }
    s = wave_reduce_f(s);
    if (lane == 0) {
      float tt = Dv - __uint_as_float(P);
      if (tt < 0.f) tt = 0.f;
      atomicAdd(out, (s + (float)(KK - c) * tt) * (1.0f / (float)(NA * KK)));
    }
  }
}

// ---------------- fallback: fused (no workspace), block-wide ----------------

__device__ __forceinline__ float compute_D_block(
    const float* __restrict__ out1, const float* __restrict__ out2,
    const int* __restrict__ anchor1, const int* __restrict__ anchor2, int a) {
  __shared__ float dred[4];
  const int tid = threadIdx.x;
  float p = 0.f;
  if (tid < DF) {
    const int r1 = anchor1[a];
    const int r2 = anchor2[a];
    p = fabsf(out1[(size_t)r1 * DF + tid] - out2[(size_t)r2 * DF + tid]);
  }
  p = wave_reduce_f(p);
  const int lane = tid & 63, wid = tid >> 6;
  if (lane == 0) dred[wid] = p;
  __syncthreads();
  return dred[0] + dred[1] + dred[2] + dred[3] + 1.0f;
}

__global__ __launch_bounds__(256) void fused_kernel(
    const float* __restrict__ out1, const float* __restrict__ out2,
    const int* __restrict__ anchor1, const int* __restrict__ anchor2,
    float* __restrict__ out) {
  const int tid = threadIdx.x;
  const int row = blockIdx.x;  // 0..1023
  const int dir = row >> 9;
  const int a = row & (NA - 1);
  const float* nodes = dir ? out1 : out2;
  const float* asrc = dir ? out2 : out1;
  const int* aidx = dir ? anchor2 : anchor1;

  __shared__ float ars[DF];
  __shared__ int redi[4];
  __shared__ float redf[4];
  if (tid < DF / 4) {
    const int arow = aidx[a];
    *(float4*)&ars[tid * 4] =
        *(const float4*)(asrc + (size_t)arow * DF + tid * 4);
  }
  __syncthreads();

  unsigned u[32];
  for (int i = 0; i < 32; ++i) {
    const int n = tid + 256 * i;
    const float4* nrow = (const float4*)(nodes + (size_t)n * DF);
    float dsum = 0.f;
    for (int d4 = 0; d4 < DF / 4; ++d4) {
      const float4 t = nrow[d4];
      const float4 av = *(const float4*)&ars[d4 * 4];
      dsum += fabsf(t.x - av.x) + fabsf(t.y - av.y) + fabsf(t.z - av.z) +
              fabsf(t.w - av.w);
    }
    u[i] = __float_as_uint(dsum);
  }
  __syncthreads();

  const float Dv = compute_D_block(out1, out2, anchor1, anchor2, a);
  const int lane = tid & 63, wid = tid >> 6;

  unsigned P = 0;
#pragma unroll 1
  for (int b = 30; b >= 0; --b) {
    const unsigned mid = P | (1u << b);
    int c = 0;
#pragma unroll
    for (int i = 0; i < 32; ++i) c += (u[i] < mid) ? 1 : 0;
    c = wave_reduce_i(c);
    __syncthreads();
    if (lane == 0) redi[wid] = c;
    __syncthreads();
    const int tot = redi[0] + redi[1] + redi[2] + redi[3];
    if (tot < KK) P = mid;
  }

  float s = 0.f;
  int c = 0;
#pragma unroll
  for (int i = 0; i < 32; ++i) {
    if (u[i] < P) {
      const float t = Dv - __uint_as_float(u[i]);
      s += (t > 0.f) ? t : 0.f;
      c += 1;
    }
  }
  s = wave_reduce_f(s);
  c = wave_reduce_i(c);
  __syncthreads();
  if (lane == 0) {
    redf[wid] = s;
    redi[wid] = c;
  }
  __syncthreads();
  if (tid == 0) {
    float stot = redf[0] + redf[1] + redf[2] + redf[3];
    const int ctot = redi[0] + redi[1] + redi[2] + redi[3];
    float tt = Dv - __uint_as_float(P);
    if (tt < 0.f) tt = 0.f;
    stot += (float)(KK - ctot) * tt;
    atomicAdd(out, stot * (1.0f / (float)(NA * KK)));
  }
}

// ---------------- launch ----------------

extern "C" void kernel_launch(void* const* d_in, const int* in_sizes, int n_in,
                              void* d_out, int out_size, void* d_ws,
                              size_t ws_size, hipStream_t stream) {
  const float* out1 = (const float*)d_in[0];
  const float* out2 = (const float*)d_in[1];
  const int* anchor1 = (const int*)d_in[2];
  const int* anchor2 = (const int*)d_in[3];
  float* out = (float*)d_out;

  (void)hipMemsetAsync(d_out, 0, sizeof(float), stream);

  const size_t need = (size_t)2 * NA * NN * sizeof(float);  // 32 MB
  if (ws_size >= need) {
    float* dist = (float*)d_ws;
    dim3 g1(NN / 128, NA / 64, 2);
    dist_kernel<<<g1, 256, 0, stream>>>(out1, out2, anchor1, anchor2, dist);
    select_kernel<<<2 * NA, 64, 0, stream>>>(dist, out1, out2, anchor1,
                                             anchor2, out);
  } else {
    fused_kernel<<<2 * NA, 256, 0, stream>>>(out1, out2, anchor1, anchor2, out);
  }
}

// Round 8
// 149.320 us; speedup vs baseline: 1.3132x; 1.0415x over previous
//
#include <hip/hip_runtime.h>

// RankingLoss on MI355X.
// inputs: out1 [8192,128] f32, out2 [8192,128] f32, anchor1 [512] i32, anchor2 [512] i32
// output: scalar f32 loss.
//
// R8: (a) dist core switched to u16 quantization + v_sad_u16 (2 dims +
// accumulate in ONE inst vs 3 for the f16 pk_sub/and/fdot2 chain). Quant:
// q = (x+8)*4096 (biased, offset cancels in |qa-qb|); err <= 128/4096 ~ 0.03
// per distance (better than f16's 0.25). (b) tile 128x128 (8x8 acc, 512
// blocks): 1.0 B LDS-read per sad vs 1.5 -- the per-CU LDS pipe (shared by
// 4 SIMDs) was the next limiter once VALU dropped 3x. (c) select: 256
// threads/block (16 waves/CU for L2-latency hiding); T = 32nd-smallest of 64
// partition-minima (4 thread-mins folded per partition), E[cand]~44; exact
// final search by wave 0 over LDS candidates.

#define NN 8192      // nodes
#define DF 128       // feature dim
#define NA 512       // anchors
#define KK 32        // negatives per anchor
#define CCAP 256     // candidate capacity (E[C]~44; fallback if exceeded)

// ---------------- helpers ----------------

__device__ __forceinline__ float wave_reduce_f(float x) {
#pragma unroll
  for (int off = 32; off > 0; off >>= 1) x += __shfl_down(x, off);
  return x;
}

__device__ __forceinline__ int wave_reduce_i(int x) {
#pragma unroll
  for (int off = 32; off > 0; off >>= 1) x += __shfl_down(x, off);
  return x;
}

__device__ __forceinline__ unsigned umin2(unsigned a, unsigned b) {
  return a < b ? a : b;
}

// acc += |a.lo16-b.lo16| + |a.hi16-b.hi16|  (one v_sad_u16)
__device__ __forceinline__ unsigned sad16(unsigned a, unsigned b,
                                          unsigned acc) {
#if __has_builtin(__builtin_amdgcn_sad_u16)
  return __builtin_amdgcn_sad_u16(a, b, acc);
#else
  const unsigned al = a & 0xFFFFu, bl = b & 0xFFFFu;
  const unsigned ah = a >> 16, bh = b >> 16;
  acc += (al > bl) ? (al - bl) : (bl - al);
  acc += (ah > bh) ? (ah - bh) : (bh - ah);
  return acc;
#endif
}

// two f32 dims -> packed biased u16 pair: q = round((x+8)*4096)
__device__ __forceinline__ unsigned q2(float x, float y) {
  const unsigned lo = (unsigned)fmaf(x, 4096.0f, 32768.5f);
  const unsigned hi = (unsigned)fmaf(y, 4096.0f, 32768.5f);
  return lo | (hi << 16);
}

// 8 dims (two float4) -> uint4 of packed u16 pairs
__device__ __forceinline__ uint4 quant8(float4 a, float4 b) {
  uint4 r;
  r.x = q2(a.x, a.y);
  r.y = q2(a.z, a.w);
  r.z = q2(b.x, b.y);
  r.w = q2(b.z, b.w);
  return r;
}

// ---------------- kernel 1: distance matrix ----------------
// grid: (64 node tiles, 4 anchor tiles, 2 dirs) = 512 blocks, block 256.
// Tile: 128 nodes x 128 anchors; dims chunked by 32 through LDS as packed
// u16 (stride 20 uints; b128 reads/writes <=2-way banked). 8x8 u32 sad acc.
// Epilogue: 4 quarters of 32 rows through LDS, coalesced dwordx4 stores.

__global__ __launch_bounds__(256) void dist_kernel(
    const float* __restrict__ out1, const float* __restrict__ out2,
    const int* __restrict__ anchor1, const int* __restrict__ anchor2,
    float* __restrict__ dist) {
  const int tid = threadIdx.x;
  const int nb = blockIdx.x;   // node tile
  const int ab = blockIdx.y;   // anchor tile
  const int dir = blockIdx.z;  // 0: a1 vs out2, 1: a2 vs out1
  const float* nodes = dir ? out1 : out2;
  const float* asrc = dir ? out2 : out1;
  const int* aidx = dir ? anchor2 : anchor1;
  const int n0 = nb * 128;
  const int a0 = ab * 128;

  __shared__ union {
    struct {
      unsigned nds[128][20];  // node rows: 16 uints = 32 u16 dims + pad
      unsigned ads[128][20];  // anchor rows
    } t;
    float stage[32][136];  // epilogue transpose staging (2-way banks, free)
  } sm;
  __shared__ int aind[128];

  if (tid < 128) aind[tid] = aidx[a0 + tid];

  unsigned acc[8][8];
#pragma unroll
  for (int i = 0; i < 8; ++i)
#pragma unroll
    for (int j = 0; j < 8; ++j) acc[i][j] = 0u;

  const int tn = tid & 15;  // node group:   cols tn + 16*i
  const int ta = tid >> 4;  // anchor group: rows ta + 16*j

#pragma unroll 1
  for (int cch = 0; cch < 4; ++cch) {
    const int d0 = cch * 32;
    __syncthreads();  // prev chunk's readers done (also covers aind preload)
    // Node tile: 128 rows x 4 uint4-slots = 512 slots; 2 per thread.
#pragma unroll
    for (int r = 0; r < 2; ++r) {
      const int f = tid + 256 * r;
      const int row = f >> 2;  // 0..127
      const int q = f & 3;     // 0..3 (8 dims each)
      const float* src = nodes + (size_t)(n0 + row) * DF + d0 + q * 8;
      const float4 v0 = *(const float4*)(src);
      const float4 v1 = *(const float4*)(src + 4);
      *(uint4*)&sm.t.nds[row][q * 4] = quant8(v0, v1);  // ds_write_b128
    }
    // Anchor tile: 128 rows x 4 slots = 512 slots; 2 per thread.
#pragma unroll
    for (int r = 0; r < 2; ++r) {
      const int g = tid + 256 * r;
      const int row = g >> 2;  // 0..127
      const int q = g & 3;
      const float* src = asrc + (size_t)aind[row] * DF + d0 + q * 8;
      const float4 v0 = *(const float4*)(src);
      const float4 v1 = *(const float4*)(src + 4);
      *(uint4*)&sm.t.ads[row][q * 4] = quant8(v0, v1);
    }
    __syncthreads();
#pragma unroll
    for (int d8 = 0; d8 < 4; ++d8) {  // 8 dims (4 uints) per step
      uint4 nv[8], av[8];
#pragma unroll
      for (int i = 0; i < 8; ++i)
        nv[i] = *(const uint4*)&sm.t.nds[tn + 16 * i][d8 * 4];
#pragma unroll
      for (int j = 0; j < 8; ++j)
        av[j] = *(const uint4*)&sm.t.ads[ta + 16 * j][d8 * 4];
#pragma unroll
      for (int i = 0; i < 8; ++i)
#pragma unroll
        for (int j = 0; j < 8; ++j) {
          unsigned s = sad16(nv[i].x, av[j].x, acc[i][j]);
          s = sad16(nv[i].y, av[j].y, s);
          s = sad16(nv[i].z, av[j].z, s);
          acc[i][j] = sad16(nv[i].w, av[j].w, s);
        }
    }
  }

  // Epilogue: four 32-row quarters through LDS, coalesced dwordx4 stores.
  const float inv = 1.0f / 4096.0f;
  const size_t rowbase = (size_t)(dir * NA + a0) * NN + n0;
#pragma unroll 1
  for (int qd = 0; qd < 4; ++qd) {
    __syncthreads();  // tiles / previous stage fully consumed
#pragma unroll
    for (int jj = 0; jj < 2; ++jj) {
      const int j = 2 * qd + jj;
#pragma unroll
      for (int i = 0; i < 8; ++i)
        sm.stage[ta + 16 * jj][tn + 16 * i] = (float)acc[i][j] * inv;
    }
    __syncthreads();
#pragma unroll
    for (int s = 0; s < 4; ++s) {
      const int f = tid + 256 * s;  // 0..1023 float4 slots
      const int row = f >> 5;       // 0..31
      const int c4 = f & 31;        // 0..31
      const float4 v = *(const float4*)&sm.stage[row][c4 * 4];
      *(float4*)(dist + rowbase + (size_t)(32 * qd + row) * NN + c4 * 4) = v;
    }
  }
}

// ---------------- kernel 2: selection + loss ----------------
// grid: 1024 blocks x 256 threads (4 waves/row => 16 waves/CU hides L2
// latency). Pass 1: per-thread min; T = exact 32nd-smallest of 64
// partition-minima (threads {p,p+64,p+128,p+192} partition the row).
// Pass 2: compact candidates (<=T) to LDS; wave 0 does exact bitwise
// search + tie-analytic loss. Streaming fallback if C > CCAP (adversarial).

__global__ __launch_bounds__(256) void select_kernel(
    const float* __restrict__ dist, const float* __restrict__ out1,
    const float* __restrict__ out2, const int* __restrict__ anchor1,
    const int* __restrict__ anchor2, float* __restrict__ out) {
  const int tid = threadIdx.x;
  const int lane = tid & 63, w = tid >> 6;
  const int row = blockIdx.x;  // 0..1023
  const int a = row & (NA - 1);

  __shared__ unsigned mins[256];
  __shared__ unsigned cand[CCAP];
  __shared__ int cnt;
  __shared__ unsigned Tsh;
  __shared__ float dred[2];

  const uint4* drow = (const uint4*)(dist + (size_t)row * NN);

  // D = L1(out1[anchor1[a]], out2[anchor2[a]]) + margin, exact f32 (128 thr).
  {
    float p = 0.f;
    if (tid < DF) {
      const int r1 = anchor1[a];
      const int r2 = anchor2[a];
      p = fabsf(out1[(size_t)r1 * DF + tid] - out2[(size_t)r2 * DF + tid]);
    }
    p = wave_reduce_f(p);
    if (tid < DF && lane == 0) dred[w] = p;
  }
  if (tid == 0) cnt = 0;

  // Pass 1: per-thread min over its 32 values (8 uint4, indep chains).
  unsigned m0 = 0xFFFFFFFFu, m1 = 0xFFFFFFFFu, m2 = 0xFFFFFFFFu,
           m3 = 0xFFFFFFFFu;
#pragma unroll
  for (int g = 0; g < 8; ++g) {
    const uint4 t = drow[tid + 256 * g];
    m0 = umin2(m0, t.x);
    m1 = umin2(m1, t.y);
    m2 = umin2(m2, t.z);
    m3 = umin2(m3, t.w);
  }
  mins[tid] = umin2(umin2(m0, m1), umin2(m2, m3));
  __syncthreads();

  // Wave 0: T = exact 32nd smallest of the 64 partition minima.
  if (w == 0) {
    const unsigned pm =
        umin2(umin2(mins[lane], mins[lane + 64]),
              umin2(mins[lane + 128], mins[lane + 192]));
    unsigned T = 0;
#pragma unroll 1
    for (int b = 30; b >= 0; --b) {
      const unsigned mid = T | (1u << b);
      if ((int)__popcll(__ballot(pm < mid)) < KK) T = mid;
    }
    if (lane == 0) Tsh = T;
  }
  __syncthreads();
  const unsigned T = Tsh;

  // Pass 2: compact candidates (u <= T) into LDS (block atomics).
#pragma unroll
  for (int g = 0; g < 8; ++g) {
    const uint4 t = drow[tid + 256 * g];
    if (t.x <= T) { int q = atomicAdd(&cnt, 1); if (q < CCAP) cand[q] = t.x; }
    if (t.y <= T) { int q = atomicAdd(&cnt, 1); if (q < CCAP) cand[q] = t.y; }
    if (t.z <= T) { int q = atomicAdd(&cnt, 1); if (q < CCAP) cand[q] = t.z; }
    if (t.w <= T) { int q = atomicAdd(&cnt, 1); if (q < CCAP) cand[q] = t.w; }
  }
  __syncthreads();
  const int C = cnt;
  const float Dv = dred[0] + dred[1] + 1.0f;  // MARGIN

  if (w != 0) return;  // wave 0 finishes alone (no barriers below)

  if (C <= CCAP) {
    unsigned v[4];
#pragma unroll
    for (int k = 0; k < 4; ++k)
      v[k] = (lane + 64 * k < C) ? cand[lane + 64 * k] : 0xFFFFFFFFu;

    // Counts over candidates == full-row counts for probes <= T; probes > T
    // return >=32 either way. Search exact.
    unsigned P = 0;
#pragma unroll 1
    for (int b = 30; b >= 0; --b) {
      const unsigned mid = P | (1u << b);
      int c = 0;
#pragma unroll
      for (int k = 0; k < 4; ++k) c += (int)__popcll(__ballot(v[k] < mid));
      if (c < KK) P = mid;
    }

    float s = 0.f;
    int c = 0;
#pragma unroll
    for (int k = 0; k < 4; ++k) {
      c += (int)__popcll(__ballot(v[k] < P));
      if (v[k] < P) {
        const float t = Dv - __uint_as_float(v[k]);
        s += (t > 0.f) ? t : 0.f;
      }
    }
    s = wave_reduce_f(s);
    if (lane == 0) {
      float tt = Dv - __uint_as_float(P);
      if (tt < 0.f) tt = 0.f;
      atomicAdd(out, (s + (float)(KK - c) * tt) * (1.0f / (float)(NA * KK)));
    }
  } else {
    // Fallback (adversarial/degenerate rows only): wave-0 streaming search.
    unsigned P = 0;
#pragma unroll 1
    for (int b = 30; b >= 0; --b) {
      const unsigned mid = P | (1u << b);
      int c = 0;
#pragma unroll 1
      for (int g = 0; g < 32; ++g) {
        const uint4 t = drow[lane + 64 * g];
        c += (int)__popcll(__ballot(t.x < mid));
        c += (int)__popcll(__ballot(t.y < mid));
        c += (int)__popcll(__ballot(t.z < mid));
        c += (int)__popcll(__ballot(t.w < mid));
      }
      if (c < KK) P = mid;
    }
    float s = 0.f;
    int c = 0;
#pragma unroll 1
    for (int g = 0; g < 32; ++g) {
      const uint4 t = drow[lane + 64 * g];
      const unsigned vv[4] = {t.x, t.y, t.z, t.w};
#pragma unroll
      for (int k = 0; k < 4; ++k) {
        c += (int)__popcll(__ballot(vv[k] < P));
        if (vv[k] < P) {
          const float tt = Dv - __uint_as_float(vv[k]);
          s += (tt > 0.f) ? tt : 0.f;
        }
      }
    }
    s = wave_reduce_f(s);
    if (lane == 0) {
      float tt = Dv - __uint_as_float(P);
      if (tt < 0.f) tt = 0.f;
      atomicAdd(out, (s + (float)(KK - c) * tt) * (1.0f / (float)(NA * KK)));
    }
  }
}

// ---------------- fallback: fused (no workspace), block-wide ----------------

__device__ __forceinline__ float compute_D_block(
    const float* __restrict__ out1, const float* __restrict__ out2,
    const int* __restrict__ anchor1, const int* __restrict__ anchor2, int a) {
  __shared__ float dred[4];
  const int tid = threadIdx.x;
  float p = 0.f;
  if (tid < DF) {
    const int r1 = anchor1[a];
    const int r2 = anchor2[a];
    p = fabsf(out1[(size_t)r1 * DF + tid] - out2[(size_t)r2 * DF + tid]);
  }
  p = wave_reduce_f(p);
  const int lane = tid & 63, wid = tid >> 6;
  if (lane == 0) dred[wid] = p;
  __syncthreads();
  return dred[0] + dred[1] + dred[2] + dred[3] + 1.0f;
}

__global__ __launch_bounds__(256) void fused_kernel(
    const float* __restrict__ out1, const float* __restrict__ out2,
    const int* __restrict__ anchor1, const int* __restrict__ anchor2,
    float* __restrict__ out) {
  const int tid = threadIdx.x;
  const int row = blockIdx.x;  // 0..1023
  const int dir = row >> 9;
  const int a = row & (NA - 1);
  const float* nodes = dir ? out1 : out2;
  const float* asrc = dir ? out2 : out1;
  const int* aidx = dir ? anchor2 : anchor1;

  __shared__ float ars[DF];
  __shared__ int redi[4];
  __shared__ float redf[4];
  if (tid < DF / 4) {
    const int arow = aidx[a];
    *(float4*)&ars[tid * 4] =
        *(const float4*)(asrc + (size_t)arow * DF + tid * 4);
  }
  __syncthreads();

  unsigned u[32];
  for (int i = 0; i < 32; ++i) {
    const int n = tid + 256 * i;
    const float4* nrow = (const float4*)(nodes + (size_t)n * DF);
    float dsum = 0.f;
    for (int d4 = 0; d4 < DF / 4; ++d4) {
      const float4 t = nrow[d4];
      const float4 av = *(const float4*)&ars[d4 * 4];
      dsum += fabsf(t.x - av.x) + fabsf(t.y - av.y) + fabsf(t.z - av.z) +
              fabsf(t.w - av.w);
    }
    u[i] = __float_as_uint(dsum);
  }
  __syncthreads();

  const float Dv = compute_D_block(out1, out2, anchor1, anchor2, a);
  const int lane = tid & 63, wid = tid >> 6;

  unsigned P = 0;
#pragma unroll 1
  for (int b = 30; b >= 0; --b) {
    const unsigned mid = P | (1u << b);
    int c = 0;
#pragma unroll
    for (int i = 0; i < 32; ++i) c += (u[i] < mid) ? 1 : 0;
    c = wave_reduce_i(c);
    __syncthreads();
    if (lane == 0) redi[wid] = c;
    __syncthreads();
    const int tot = redi[0] + redi[1] + redi[2] + redi[3];
    if (tot < KK) P = mid;
  }

  float s = 0.f;
  int c = 0;
#pragma unroll
  for (int i = 0; i < 32; ++i) {
    if (u[i] < P) {
      const float t = Dv - __uint_as_float(u[i]);
      s += (t > 0.f) ? t : 0.f;
      c += 1;
    }
  }
  s = wave_reduce_f(s);
  c = wave_reduce_i(c);
  __syncthreads();
  if (lane == 0) {
    redf[wid] = s;
    redi[wid] = c;
  }
  __syncthreads();
  if (tid == 0) {
    float stot = redf[0] + redf[1] + redf[2] + redf[3];
    const int ctot = redi[0] + redi[1] + redi[2] + redi[3];
    float tt = Dv - __uint_as_float(P);
    if (tt < 0.f) tt = 0.f;
    stot += (float)(KK - ctot) * tt;
    atomicAdd(out, stot * (1.0f / (float)(NA * KK)));
  }
}

// ---------------- launch ----------------

extern "C" void kernel_launch(void* const* d_in, const int* in_sizes, int n_in,
                              void* d_out, int out_size, void* d_ws,
                              size_t ws_size, hipStream_t stream) {
  const float* out1 = (const float*)d_in[0];
  const float* out2 = (const float*)d_in[1];
  const int* anchor1 = (const int*)d_in[2];
  const int* anchor2 = (const int*)d_in[3];
  float* out = (float*)d_out;

  (void)hipMemsetAsync(d_out, 0, sizeof(float), stream);

  const size_t need = (size_t)2 * NA * NN * sizeof(float);  // 32 MB
  if (ws_size >= need) {
    float* dist = (float*)d_ws;
    dim3 g1(NN / 128, NA / 128, 2);
    dist_kernel<<<g1, 256, 0, stream>>>(out1, out2, anchor1, anchor2, dist);
    select_kernel<<<2 * NA, 256, 0, stream>>>(dist, out1, out2, anchor1,
                                              anchor2, out);
  } else {
    fused_kernel<<<2 * NA, 256, 0, stream>>>(out1, out2, anchor1, anchor2, out);
  }
}

// Round 9
// 137.940 us; speedup vs baseline: 1.4215x; 1.0825x over previous
//
#include <hip/hip_runtime.h>

// RankingLoss on MI355X.
// inputs: out1 [8192,128] f32, out2 [8192,128] f32, anchor1 [512] i32, anchor2 [512] i32
// output: scalar f32 loss.
//
// R9: R8's 128x128 tile SPILLED (VGPR_Count 136 < ~160 live: WRITE_SIZE
// 105MB vs 32MB matrix, VALUBusy 21%, duration unchanged) -- same failure
// mode as R2. Revert to R7's proven no-spill shape (128x64 tile, 8x4 acc,
// VGPR 84, launch_bounds(256,3), 1024 blocks) while KEEPING R8's u16
// v_sad_u16 core (1 inst per 2 dims vs 3 for f16 chain; absmax 0.0).
// Select unchanged from R8 (256 thr/block, partition-min prefilter).

#define NN 8192      // nodes
#define DF 128       // feature dim
#define NA 512       // anchors
#define KK 32        // negatives per anchor
#define CCAP 256     // candidate capacity (E[C]~44; fallback if exceeded)

// ---------------- helpers ----------------

__device__ __forceinline__ float wave_reduce_f(float x) {
#pragma unroll
  for (int off = 32; off > 0; off >>= 1) x += __shfl_down(x, off);
  return x;
}

__device__ __forceinline__ int wave_reduce_i(int x) {
#pragma unroll
  for (int off = 32; off > 0; off >>= 1) x += __shfl_down(x, off);
  return x;
}

__device__ __forceinline__ unsigned umin2(unsigned a, unsigned b) {
  return a < b ? a : b;
}

// acc += |a.lo16-b.lo16| + |a.hi16-b.hi16|  (one v_sad_u16)
__device__ __forceinline__ unsigned sad16(unsigned a, unsigned b,
                                          unsigned acc) {
#if __has_builtin(__builtin_amdgcn_sad_u16)
  return __builtin_amdgcn_sad_u16(a, b, acc);
#else
  const unsigned al = a & 0xFFFFu, bl = b & 0xFFFFu;
  const unsigned ah = a >> 16, bh = b >> 16;
  acc += (al > bl) ? (al - bl) : (bl - al);
  acc += (ah > bh) ? (ah - bh) : (bh - ah);
  return acc;
#endif
}

// two f32 dims -> packed biased u16 pair: q = round((x+8)*4096)
__device__ __forceinline__ unsigned q2(float x, float y) {
  const unsigned lo = (unsigned)fmaf(x, 4096.0f, 32768.5f);
  const unsigned hi = (unsigned)fmaf(y, 4096.0f, 32768.5f);
  return lo | (hi << 16);
}

// 8 dims (two float4) -> uint4 of packed u16 pairs
__device__ __forceinline__ uint4 quant8(float4 a, float4 b) {
  uint4 r;
  r.x = q2(a.x, a.y);
  r.y = q2(a.z, a.w);
  r.z = q2(b.x, b.y);
  r.w = q2(b.z, b.w);
  return r;
}

// ---------------- kernel 1: distance matrix ----------------
// grid: (64 node tiles, 8 anchor tiles, 2 dirs) = 1024 blocks, block 256.
// Tile: 128 nodes x 64 anchors; dims chunked by 32 through LDS as packed u16
// (stride 20 uints; b128 reads/writes <=2-way banked). 8x4 u32 sad acc
// (~100 live VGPRs -- fits the (256,3) cap of 170 without spill).
// Epilogue: two 32-row halves through LDS, coalesced dwordx4 stores.

__global__ __launch_bounds__(256, 3) void dist_kernel(
    const float* __restrict__ out1, const float* __restrict__ out2,
    const int* __restrict__ anchor1, const int* __restrict__ anchor2,
    float* __restrict__ dist) {
  const int tid = threadIdx.x;
  const int nb = blockIdx.x;   // node tile
  const int ab = blockIdx.y;   // anchor tile
  const int dir = blockIdx.z;  // 0: a1 vs out2, 1: a2 vs out1
  const float* nodes = dir ? out1 : out2;
  const float* asrc = dir ? out2 : out1;
  const int* aidx = dir ? anchor2 : anchor1;
  const int n0 = nb * 128;
  const int a0 = ab * 64;

  __shared__ union {
    struct {
      unsigned nds[128][20];  // node rows: 16 uints = 32 u16 dims + pad
      unsigned ads[64][20];   // anchor rows
    } t;
    float stage[32][136];  // epilogue transpose staging (2-way banks, free)
  } sm;
  __shared__ int aind[64];

  if (tid < 64) aind[tid] = aidx[a0 + tid];

  unsigned acc[8][4];
#pragma unroll
  for (int i = 0; i < 8; ++i)
#pragma unroll
    for (int j = 0; j < 4; ++j) acc[i][j] = 0u;

  const int tn = tid & 15;  // node group:   cols tn + 16*i
  const int ta = tid >> 4;  // anchor group: rows ta + 16*j

#pragma unroll 1
  for (int cch = 0; cch < 4; ++cch) {
    const int d0 = cch * 32;
    __syncthreads();  // prev chunk's readers done (also covers aind preload)
    // Node tile: 128 rows x 4 uint4-slots = 512 slots; 2 per thread.
#pragma unroll
    for (int r = 0; r < 2; ++r) {
      const int f = tid + 256 * r;
      const int row = f >> 2;  // 0..127
      const int q = f & 3;     // 0..3 (8 dims each)
      const float* src = nodes + (size_t)(n0 + row) * DF + d0 + q * 8;
      const float4 v0 = *(const float4*)(src);
      const float4 v1 = *(const float4*)(src + 4);
      *(uint4*)&sm.t.nds[row][q * 4] = quant8(v0, v1);  // ds_write_b128
    }
    // Anchor tile: 64 rows x 4 slots = 256 slots; 1 per thread.
    {
      const int row = tid >> 2;  // 0..63
      const int q = tid & 3;
      const float* src = asrc + (size_t)aind[row] * DF + d0 + q * 8;
      const float4 v0 = *(const float4*)(src);
      const float4 v1 = *(const float4*)(src + 4);
      *(uint4*)&sm.t.ads[row][q * 4] = quant8(v0, v1);
    }
    __syncthreads();
#pragma unroll
    for (int d8 = 0; d8 < 4; ++d8) {  // 8 dims (4 uints) per step
      uint4 nv[8], av[4];
#pragma unroll
      for (int i = 0; i < 8; ++i)
        nv[i] = *(const uint4*)&sm.t.nds[tn + 16 * i][d8 * 4];
#pragma unroll
      for (int j = 0; j < 4; ++j)
        av[j] = *(const uint4*)&sm.t.ads[ta + 16 * j][d8 * 4];
#pragma unroll
      for (int i = 0; i < 8; ++i)
#pragma unroll
        for (int j = 0; j < 4; ++j) {
          unsigned s = sad16(nv[i].x, av[j].x, acc[i][j]);
          s = sad16(nv[i].y, av[j].y, s);
          s = sad16(nv[i].z, av[j].z, s);
          acc[i][j] = sad16(nv[i].w, av[j].w, s);
        }
    }
  }

  // Epilogue: two 32-row halves through LDS, coalesced dwordx4 stores.
  const float inv = 1.0f / 4096.0f;
  const size_t rowbase = (size_t)(dir * NA + a0) * NN + n0;
#pragma unroll 1
  for (int half = 0; half < 2; ++half) {
    __syncthreads();  // tiles / previous stage fully consumed
#pragma unroll
    for (int j = 0; j < 2; ++j) {
      const int jj = half * 2 + j;
#pragma unroll
      for (int i = 0; i < 8; ++i)
        sm.stage[ta + 16 * j][tn + 16 * i] = (float)acc[i][jj] * inv;
    }
    __syncthreads();
#pragma unroll
    for (int s = 0; s < 4; ++s) {
      const int f = tid + 256 * s;  // 0..1023 float4 slots
      const int row = f >> 5;       // 0..31
      const int c4 = f & 31;        // 0..31
      const float4 v = *(const float4*)&sm.stage[row][c4 * 4];
      *(float4*)(dist + rowbase + (size_t)(half * 32 + row) * NN + c4 * 4) = v;
    }
  }
}

// ---------------- kernel 2: selection + loss (unchanged from R8) -----------
// grid: 1024 blocks x 256 threads (16 waves/CU hides L2 latency).
// Pass 1: per-thread min; T = exact 32nd-smallest of 64 partition-minima.
// Pass 2: compact candidates (<=T) to LDS; wave 0 exact bitwise search +
// tie-analytic loss. Streaming fallback if C > CCAP (adversarial only).

__global__ __launch_bounds__(256) void select_kernel(
    const float* __restrict__ dist, const float* __restrict__ out1,
    const float* __restrict__ out2, const int* __restrict__ anchor1,
    const int* __restrict__ anchor2, float* __restrict__ out) {
  const int tid = threadIdx.x;
  const int lane = tid & 63, w = tid >> 6;
  const int row = blockIdx.x;  // 0..1023
  const int a = row & (NA - 1);

  __shared__ unsigned mins[256];
  __shared__ unsigned cand[CCAP];
  __shared__ int cnt;
  __shared__ unsigned Tsh;
  __shared__ float dred[2];

  const uint4* drow = (const uint4*)(dist + (size_t)row * NN);

  // D = L1(out1[anchor1[a]], out2[anchor2[a]]) + margin, exact f32 (128 thr).
  {
    float p = 0.f;
    if (tid < DF) {
      const int r1 = anchor1[a];
      const int r2 = anchor2[a];
      p = fabsf(out1[(size_t)r1 * DF + tid] - out2[(size_t)r2 * DF + tid]);
    }
    p = wave_reduce_f(p);
    if (tid < DF && lane == 0) dred[w] = p;
  }
  if (tid == 0) cnt = 0;

  // Pass 1: per-thread min over its 32 values (8 uint4, indep chains).
  unsigned m0 = 0xFFFFFFFFu, m1 = 0xFFFFFFFFu, m2 = 0xFFFFFFFFu,
           m3 = 0xFFFFFFFFu;
#pragma unroll
  for (int g = 0; g < 8; ++g) {
    const uint4 t = drow[tid + 256 * g];
    m0 = umin2(m0, t.x);
    m1 = umin2(m1, t.y);
    m2 = umin2(m2, t.z);
    m3 = umin2(m3, t.w);
  }
  mins[tid] = umin2(umin2(m0, m1), umin2(m2, m3));
  __syncthreads();

  // Wave 0: T = exact 32nd smallest of the 64 partition minima.
  if (w == 0) {
    const unsigned pm =
        umin2(umin2(mins[lane], mins[lane + 64]),
              umin2(mins[lane + 128], mins[lane + 192]));
    unsigned T = 0;
#pragma unroll 1
    for (int b = 30; b >= 0; --b) {
      const unsigned mid = T | (1u << b);
      if ((int)__popcll(__ballot(pm < mid)) < KK) T = mid;
    }
    if (lane == 0) Tsh = T;
  }
  __syncthreads();
  const unsigned T = Tsh;

  // Pass 2: compact candidates (u <= T) into LDS (block atomics).
#pragma unroll
  for (int g = 0; g < 8; ++g) {
    const uint4 t = drow[tid + 256 * g];
    if (t.x <= T) { int q = atomicAdd(&cnt, 1); if (q < CCAP) cand[q] = t.x; }
    if (t.y <= T) { int q = atomicAdd(&cnt, 1); if (q < CCAP) cand[q] = t.y; }
    if (t.z <= T) { int q = atomicAdd(&cnt, 1); if (q < CCAP) cand[q] = t.z; }
    if (t.w <= T) { int q = atomicAdd(&cnt, 1); if (q < CCAP) cand[q] = t.w; }
  }
  __syncthreads();
  const int C = cnt;
  const float Dv = dred[0] + dred[1] + 1.0f;  // MARGIN

  if (w != 0) return;  // wave 0 finishes alone (no barriers below)

  if (C <= CCAP) {
    unsigned v[4];
#pragma unroll
    for (int k = 0; k < 4; ++k)
      v[k] = (lane + 64 * k < C) ? cand[lane + 64 * k] : 0xFFFFFFFFu;

    // Counts over candidates == full-row counts for probes <= T; probes > T
    // return >=32 either way. Search exact.
    unsigned P = 0;
#pragma unroll 1
    for (int b = 30; b >= 0; --b) {
      const unsigned mid = P | (1u << b);
      int c = 0;
#pragma unroll
      for (int k = 0; k < 4; ++k) c += (int)__popcll(__ballot(v[k] < mid));
      if (c < KK) P = mid;
    }

    float s = 0.f;
    int c = 0;
#pragma unroll
    for (int k = 0; k < 4; ++k) {
      c += (int)__popcll(__ballot(v[k] < P));
      if (v[k] < P) {
        const float t = Dv - __uint_as_float(v[k]);
        s += (t > 0.f) ? t : 0.f;
      }
    }
    s = wave_reduce_f(s);
    if (lane == 0) {
      float tt = Dv - __uint_as_float(P);
      if (tt < 0.f) tt = 0.f;
      atomicAdd(out, (s + (float)(KK - c) * tt) * (1.0f / (float)(NA * KK)));
    }
  } else {
    // Fallback (adversarial/degenerate rows only): wave-0 streaming search.
    unsigned P = 0;
#pragma unroll 1
    for (int b = 30; b >= 0; --b) {
      const unsigned mid = P | (1u << b);
      int c = 0;
#pragma unroll 1
      for (int g = 0; g < 32; ++g) {
        const uint4 t = drow[lane + 64 * g];
        c += (int)__popcll(__ballot(t.x < mid));
        c += (int)__popcll(__ballot(t.y < mid));
        c += (int)__popcll(__ballot(t.z < mid));
        c += (int)__popcll(__ballot(t.w < mid));
      }
      if (c < KK) P = mid;
    }
    float s = 0.f;
    int c = 0;
#pragma unroll 1
    for (int g = 0; g < 32; ++g) {
      const uint4 t = drow[lane + 64 * g];
      const unsigned vv[4] = {t.x, t.y, t.z, t.w};
#pragma unroll
      for (int k = 0; k < 4; ++k) {
        c += (int)__popcll(__ballot(vv[k] < P));
        if (vv[k] < P) {
          const float tt = Dv - __uint_as_float(vv[k]);
          s += (tt > 0.f) ? tt : 0.f;
        }
      }
    }
    s = wave_reduce_f(s);
    if (lane == 0) {
      float tt = Dv - __uint_as_float(P);
      if (tt < 0.f) tt = 0.f;
      atomicAdd(out, (s + (float)(KK - c) * tt) * (1.0f / (float)(NA * KK)));
    }
  }
}

// ---------------- fallback: fused (no workspace), block-wide ----------------

__device__ __forceinline__ float compute_D_block(
    const float* __restrict__ out1, const float* __restrict__ out2,
    const int* __restrict__ anchor1, const int* __restrict__ anchor2, int a) {
  __shared__ float dred[4];
  const int tid = threadIdx.x;
  float p = 0.f;
  if (tid < DF) {
    const int r1 = anchor1[a];
    const int r2 = anchor2[a];
    p = fabsf(out1[(size_t)r1 * DF + tid] - out2[(size_t)r2 * DF + tid]);
  }
  p = wave_reduce_f(p);
  const int lane = tid & 63, wid = tid >> 6;
  if (lane == 0) dred[wid] = p;
  __syncthreads();
  return dred[0] + dred[1] + dred[2] + dred[3] + 1.0f;
}

__global__ __launch_bounds__(256) void fused_kernel(
    const float* __restrict__ out1, const float* __restrict__ out2,
    const int* __restrict__ anchor1, const int* __restrict__ anchor2,
    float* __restrict__ out) {
  const int tid = threadIdx.x;
  const int row = blockIdx.x;  // 0..1023
  const int dir = row >> 9;
  const int a = row & (NA - 1);
  const float* nodes = dir ? out1 : out2;
  const float* asrc = dir ? out2 : out1;
  const int* aidx = dir ? anchor2 : anchor1;

  __shared__ float ars[DF];
  __shared__ int redi[4];
  __shared__ float redf[4];
  if (tid < DF / 4) {
    const int arow = aidx[a];
    *(float4*)&ars[tid * 4] =
        *(const float4*)(asrc + (size_t)arow * DF + tid * 4);
  }
  __syncthreads();

  unsigned u[32];
  for (int i = 0; i < 32; ++i) {
    const int n = tid + 256 * i;
    const float4* nrow = (const float4*)(nodes + (size_t)n * DF);
    float dsum = 0.f;
    for (int d4 = 0; d4 < DF / 4; ++d4) {
      const float4 t = nrow[d4];
      const float4 av = *(const float4*)&ars[d4 * 4];
      dsum += fabsf(t.x - av.x) + fabsf(t.y - av.y) + fabsf(t.z - av.z) +
              fabsf(t.w - av.w);
    }
    u[i] = __float_as_uint(dsum);
  }
  __syncthreads();

  const float Dv = compute_D_block(out1, out2, anchor1, anchor2, a);
  const int lane = tid & 63, wid = tid >> 6;

  unsigned P = 0;
#pragma unroll 1
  for (int b = 30; b >= 0; --b) {
    const unsigned mid = P | (1u << b);
    int c = 0;
#pragma unroll
    for (int i = 0; i < 32; ++i) c += (u[i] < mid) ? 1 : 0;
    c = wave_reduce_i(c);
    __syncthreads();
    if (lane == 0) redi[wid] = c;
    __syncthreads();
    const int tot = redi[0] + redi[1] + redi[2] + redi[3];
    if (tot < KK) P = mid;
  }

  float s = 0.f;
  int c = 0;
#pragma unroll
  for (int i = 0; i < 32; ++i) {
    if (u[i] < P) {
      const float t = Dv - __uint_as_float(u[i]);
      s += (t > 0.f) ? t : 0.f;
      c += 1;
    }
  }
  s = wave_reduce_f(s);
  c = wave_reduce_i(c);
  __syncthreads();
  if (lane == 0) {
    redf[wid] = s;
    redi[wid] = c;
  }
  __syncthreads();
  if (tid == 0) {
    float stot = redf[0] + redf[1] + redf[2] + redf[3];
    const int ctot = redi[0] + redi[1] + redi[2] + redi[3];
    float tt = Dv - __uint_as_float(P);
    if (tt < 0.f) tt = 0.f;
    stot += (float)(KK - ctot) * tt;
    atomicAdd(out, stot * (1.0f / (float)(NA * KK)));
  }
}

// ---------------- launch ----------------

extern "C" void kernel_launch(void* const* d_in, const int* in_sizes, int n_in,
                              void* d_out, int out_size, void* d_ws,
                              size_t ws_size, hipStream_t stream) {
  const float* out1 = (const float*)d_in[0];
  const float* out2 = (const float*)d_in[1];
  const int* anchor1 = (const int*)d_in[2];
  const int* anchor2 = (const int*)d_in[3];
  float* out = (float*)d_out;

  (void)hipMemsetAsync(d_out, 0, sizeof(float), stream);

  const size_t need = (size_t)2 * NA * NN * sizeof(float);  // 32 MB
  if (ws_size >= need) {
    float* dist = (float*)d_ws;
    dim3 g1(NN / 128, NA / 64, 2);
    dist_kernel<<<g1, 256, 0, stream>>>(out1, out2, anchor1, anchor2, dist);
    select_kernel<<<2 * NA, 256, 0, stream>>>(dist, out1, out2, anchor1,
                                              anchor2, out);
  } else {
    fused_kernel<<<2 * NA, 256, 0, stream>>>(out1, out2, anchor1, anchor2, out);
  }
}